// Round 1
// baseline (1150.730 us; speedup 1.0000x reference)
//
#include <hip/hip_runtime.h>

#define T_TOK 8192
#define DIM   1024
#define DFF_  4096
#define NE    8
#define MAXT  144

typedef float  f32x4 __attribute__((ext_vector_type(4)));
typedef __bf16 b16x8 __attribute__((ext_vector_type(8)));

__device__ __forceinline__ unsigned short f2bf(float f) {
  union { float f; unsigned int u; } v; v.f = f;
  unsigned int r = v.u + 0x7fffu + ((v.u >> 16) & 1u);
  return (unsigned short)(r >> 16);
}

__device__ __forceinline__ void gload_lds16(const void* g, void* l) {
  __builtin_amdgcn_global_load_lds((const __attribute__((address_space(1))) void*)g,
                                   (__attribute__((address_space(3))) void*)l,
                                   16, 0, 0);
}

// ---------------- transpose + fp32->bf16 convert: src [E][R][C] -> dst [E][C][R] ----------------
__global__ __launch_bounds__(256) void transpose_cvt(const float* __restrict__ src,
                                                     unsigned short* __restrict__ dst,
                                                     int R, int C) {
  __shared__ float tile[64][65];
  size_t mat = (size_t)blockIdx.z * R * C;
  int c0 = blockIdx.x * 64, r0 = blockIdx.y * 64;
  int lc = threadIdx.x & 63, q = threadIdx.x >> 6;
  const float* s = src + mat + (size_t)r0 * C + c0;
#pragma unroll
  for (int i = 0; i < 16; i++) {
    int r = q + i * 4;
    tile[r][lc] = s[(size_t)r * C + lc];
  }
  __syncthreads();
  unsigned short* d = dst + mat + (size_t)c0 * R + r0;
#pragma unroll
  for (int i = 0; i < 16; i++) {
    int cc = q + i * 4;
    d[(size_t)cc * R + lc] = f2bf(tile[lc][cc]);
  }
}

// ---------------- router: logits (fp32 exact), top-2, softmax weights, bf16 x copy ----------------
__global__ __launch_bounds__(256) void router_k(const float* __restrict__ x,
                                                const float* __restrict__ Wr,
                                                const float* __restrict__ br,
                                                unsigned short* __restrict__ Xbf,
                                                int* __restrict__ top2e,
                                                float* __restrict__ top2w) {
  int wid = threadIdx.x >> 6, lane = threadIdx.x & 63;
  int t = blockIdx.x * 4 + wid;
  const float* xr = x + (size_t)t * DIM;
  unsigned short* xb = Xbf + (size_t)t * DIM;
  float s[NE];
#pragma unroll
  for (int e = 0; e < NE; e++) s[e] = 0.f;
  for (int i = 0; i < DIM / 64; i++) {
    int dd = i * 64 + lane;
    float xv = xr[dd];
    xb[dd] = f2bf(xv);
    const float* w = Wr + (size_t)dd * NE;
#pragma unroll
    for (int e = 0; e < NE; e++) s[e] += xv * w[e];
  }
#pragma unroll
  for (int m = 32; m >= 1; m >>= 1) {
#pragma unroll
    for (int e = 0; e < NE; e++) s[e] += __shfl_xor(s[e], m, 64);
  }
  if (lane == 0) {
#pragma unroll
    for (int e = 0; e < NE; e++) s[e] += br[e];
    int e0 = 0;
#pragma unroll
    for (int e = 1; e < NE; e++) if (s[e] > s[e0]) e0 = e;
    int e1 = (e0 == 0) ? 1 : 0;
#pragma unroll
    for (int e = 0; e < NE; e++) if (e != e0 && s[e] > s[e1]) e1 = e;
    float w0 = 1.f / (1.f + expf(s[e1] - s[e0]));  // softmax over (p0,p1), p0>=p1
    top2e[2 * t] = e0; top2e[2 * t + 1] = e1;
    top2w[2 * t] = w0; top2w[2 * t + 1] = 1.f - w0;
  }
}

// ---------------- per-block aggregated expert counting ----------------
__global__ __launch_bounds__(256) void count_k(const int* __restrict__ top2e,
                                               int* __restrict__ counts) {
  __shared__ int lcnt[NE];
  if (threadIdx.x < NE) lcnt[threadIdx.x] = 0;
  __syncthreads();
  int t = blockIdx.x * 256 + threadIdx.x;
  atomicAdd(&lcnt[top2e[2 * t]], 1);
  atomicAdd(&lcnt[top2e[2 * t + 1]], 1);
  __syncthreads();
  if (threadIdx.x < NE) atomicAdd(&counts[threadIdx.x], lcnt[threadIdx.x]);
}

// ---------------- scan + grouped-GEMM tile map (single thread; tiny) ----------------
__global__ void scan_build(int* __restrict__ ctrl) {
  if (threadIdx.x != 0 || blockIdx.x != 0) return;
  int* counts = ctrl;          // [8]
  int* offsets = ctrl + 8;     // [8]
  int* cursors = ctrl + 16;    // [8]
  int* ntile = ctrl + 24;      // [1]
  int* tileE = ctrl + 32;          // [MAXT]
  int* tileM = ctrl + 32 + MAXT;   // [MAXT]
  int o = 0;
  for (int e = 0; e < NE; e++) { offsets[e] = o; cursors[e] = o; o += counts[e]; }
  int nt = 0;
  for (int e = 0; e < NE; e++)
    for (int m0 = 0; m0 < counts[e]; m0 += 128) { tileE[nt] = e; tileM[nt] = m0; nt++; }
  ntile[0] = nt;
}

// ---------------- scatter tokens into per-expert lists (block-local ranks) ----------------
__global__ __launch_bounds__(256) void scatter_k(const int* __restrict__ top2e,
                                                 const float* __restrict__ top2w,
                                                 int* __restrict__ cursors,
                                                 int* __restrict__ list_tok,
                                                 float* __restrict__ list_w) {
  __shared__ int lcnt[NE];
  __shared__ int lbase[NE];
  int tid = threadIdx.x;
  if (tid < NE) lcnt[tid] = 0;
  __syncthreads();
  int t = blockIdx.x * 256 + tid;
  int e0 = top2e[2 * t], e1 = top2e[2 * t + 1];
  int r0 = atomicAdd(&lcnt[e0], 1);
  int r1 = atomicAdd(&lcnt[e1], 1);
  __syncthreads();
  if (tid < NE) lbase[tid] = atomicAdd(&cursors[tid], lcnt[tid]);
  __syncthreads();
  int p0 = lbase[e0] + r0, p1 = lbase[e1] + r1;
  list_tok[p0] = t; list_w[p0] = top2w[2 * t];
  list_tok[p1] = t; list_w[p1] = top2w[2 * t + 1];
}

// ---------------- grouped GEMM1 + fused SwiGLU: H = silu(X@W1+b1)*(X@W2+b2) ----------------
// tile 128x128, BK=64, 512 thr (8 waves, 2x4), wave tile 64x32, dual accumulators
__global__ __launch_bounds__(512) void gemm1_k(const unsigned short* __restrict__ Xbf,
                                               const unsigned short* __restrict__ W1T,
                                               const unsigned short* __restrict__ W2T,
                                               const float* __restrict__ b1,
                                               const float* __restrict__ b2,
                                               unsigned short* __restrict__ H,
                                               const int* __restrict__ list_tok,
                                               const int* __restrict__ ctrl) {
  const int* counts = ctrl; const int* offsets = ctrl + 8;
  const int* ntile = ctrl + 24;
  const int* tileE = ctrl + 32; const int* tileM = ctrl + 32 + MAXT;
  int bt = blockIdx.y;
  if (bt >= ntile[0]) return;
  int e = tileE[bt], m0 = tileM[bt];
  int Me = counts[e], off = offsets[e];
  int n0 = blockIdx.x * 128;

  __shared__ unsigned short sAll[3 * 128 * 64];  // A | B1 | B2, 48 KB
  const unsigned short* sA = sAll;
  const unsigned short* sB1 = sAll + 128 * 64;
  const unsigned short* sB2 = sAll + 2 * 128 * 64;

  int tid = threadIdx.x, lane = tid & 63, wid = tid >> 6;
  int wr = wid >> 2, wc = wid & 3;

  // 48 chunks of 1KB (A:0-15, B1:16-31, B2:32-47); 6 per wave
  const unsigned short* gsrc[6];
  unsigned ldsoff[6];
  int rowIC = lane >> 3, colE = (lane & 7) * 8;
#pragma unroll
  for (int j = 0; j < 6; j++) {
    int c = wid * 6 + j;
    ldsoff[j] = c * 512;  // ushort elements
    if (c < 16) {
      int r = c * 8 + rowIC;
      int tok = (m0 + r < Me) ? list_tok[off + m0 + r] : list_tok[off];
      gsrc[j] = Xbf + (size_t)tok * DIM + colE;
    } else if (c < 32) {
      int n = n0 + (c - 16) * 8 + rowIC;
      gsrc[j] = W1T + ((size_t)e * DFF_ + n) * DIM + colE;
    } else {
      int n = n0 + (c - 32) * 8 + rowIC;
      gsrc[j] = W2T + ((size_t)e * DFF_ + n) * DIM + colE;
    }
  }

  f32x4 acc1[4][2], acc2[4][2];
#pragma unroll
  for (int i = 0; i < 4; i++)
#pragma unroll
    for (int j = 0; j < 2; j++) {
      acc1[i][j] = f32x4{0.f, 0.f, 0.f, 0.f};
      acc2[i][j] = f32x4{0.f, 0.f, 0.f, 0.f};
    }

  for (int kt = 0; kt < DIM / 64; kt++) {
    __syncthreads();
#pragma unroll
    for (int j = 0; j < 6; j++)
      gload_lds16(gsrc[j] + kt * 64, (void*)(sAll + ldsoff[j]));
    __syncthreads();
#pragma unroll
    for (int kk = 0; kk < 2; kk++) {
      int kE = kk * 32 + (lane >> 4) * 8;
      b16x8 aF[4], bF1[2], bF2[2];
#pragma unroll
      for (int fi = 0; fi < 4; fi++)
        aF[fi] = *(const b16x8*)(sA + (wr * 64 + fi * 16 + (lane & 15)) * 64 + kE);
#pragma unroll
      for (int fj = 0; fj < 2; fj++) {
        bF1[fj] = *(const b16x8*)(sB1 + (wc * 32 + fj * 16 + (lane & 15)) * 64 + kE);
        bF2[fj] = *(const b16x8*)(sB2 + (wc * 32 + fj * 16 + (lane & 15)) * 64 + kE);
      }
#pragma unroll
      for (int fi = 0; fi < 4; fi++)
#pragma unroll
        for (int fj = 0; fj < 2; fj++) {
          acc1[fi][fj] = __builtin_amdgcn_mfma_f32_16x16x32_bf16(aF[fi], bF1[fj], acc1[fi][fj], 0, 0, 0);
          acc2[fi][fj] = __builtin_amdgcn_mfma_f32_16x16x32_bf16(aF[fi], bF2[fj], acc2[fi][fj], 0, 0, 0);
        }
    }
  }

#pragma unroll
  for (int fi = 0; fi < 4; fi++)
#pragma unroll
    for (int fj = 0; fj < 2; fj++) {
      int col = n0 + wc * 32 + fj * 16 + (lane & 15);
      float bb1 = b1[e * DFF_ + col], bb2 = b2[e * DFF_ + col];
      int rbase = wr * 64 + fi * 16 + (lane >> 4) * 4;
#pragma unroll
      for (int r = 0; r < 4; r++) {
        int rr = rbase + r;
        if (m0 + rr < Me) {
          float c1 = acc1[fi][fj][r] + bb1;
          float c2 = acc2[fi][fj][r] + bb2;
          float h = c1 * c2 / (1.f + __expf(-c1));  // silu(c1)*c2
          H[(size_t)(off + m0 + rr) * DFF_ + col] = f2bf(h);
        }
      }
    }
}

// ---------------- grouped GEMM2: y[token] += w * (H @ W3^T + b3) ----------------
__global__ __launch_bounds__(512) void gemm2_k(const unsigned short* __restrict__ H,
                                               const unsigned short* __restrict__ W3T,
                                               const float* __restrict__ b3,
                                               const int* __restrict__ list_tok,
                                               const float* __restrict__ list_w,
                                               float* __restrict__ y,
                                               const int* __restrict__ ctrl) {
  const int* counts = ctrl; const int* offsets = ctrl + 8;
  const int* ntile = ctrl + 24;
  const int* tileE = ctrl + 32; const int* tileM = ctrl + 32 + MAXT;
  int bt = blockIdx.y;
  if (bt >= ntile[0]) return;
  int e = tileE[bt], m0 = tileM[bt];
  int Me = counts[e], off = offsets[e];
  int n0 = blockIdx.x * 128;

  __shared__ unsigned short sAll[2 * 128 * 64];  // A | B, 32 KB
  const unsigned short* sA = sAll;
  const unsigned short* sB = sAll + 128 * 64;

  int tid = threadIdx.x, lane = tid & 63, wid = tid >> 6;
  int wr = wid >> 2, wc = wid & 3;

  const unsigned short* gsrc[4];
  unsigned ldsoff[4];
  int rowIC = lane >> 3, colE = (lane & 7) * 8;
#pragma unroll
  for (int j = 0; j < 4; j++) {
    int c = wid * 4 + j;
    ldsoff[j] = c * 512;
    if (c < 16) {
      int r = c * 8 + rowIC;
      int pos = (m0 + r < Me) ? (off + m0 + r) : off;
      gsrc[j] = H + (size_t)pos * DFF_ + colE;
    } else {
      int n = n0 + (c - 16) * 8 + rowIC;
      gsrc[j] = W3T + ((size_t)e * DIM + n) * DFF_ + colE;
    }
  }

  f32x4 acc[4][2];
#pragma unroll
  for (int i = 0; i < 4; i++)
#pragma unroll
    for (int j = 0; j < 2; j++) acc[i][j] = f32x4{0.f, 0.f, 0.f, 0.f};

  for (int kt = 0; kt < DFF_ / 64; kt++) {
    __syncthreads();
#pragma unroll
    for (int j = 0; j < 4; j++)
      gload_lds16(gsrc[j] + kt * 64, (void*)(sAll + ldsoff[j]));
    __syncthreads();
#pragma unroll
    for (int kk = 0; kk < 2; kk++) {
      int kE = kk * 32 + (lane >> 4) * 8;
      b16x8 aF[4], bF[2];
#pragma unroll
      for (int fi = 0; fi < 4; fi++)
        aF[fi] = *(const b16x8*)(sA + (wr * 64 + fi * 16 + (lane & 15)) * 64 + kE);
#pragma unroll
      for (int fj = 0; fj < 2; fj++)
        bF[fj] = *(const b16x8*)(sB + (wc * 32 + fj * 16 + (lane & 15)) * 64 + kE);
#pragma unroll
      for (int fi = 0; fi < 4; fi++)
#pragma unroll
        for (int fj = 0; fj < 2; fj++)
          acc[fi][fj] = __builtin_amdgcn_mfma_f32_16x16x32_bf16(aF[fi], bF[fj], acc[fi][fj], 0, 0, 0);
    }
  }

#pragma unroll
  for (int fi = 0; fi < 4; fi++)
#pragma unroll
    for (int fj = 0; fj < 2; fj++) {
      int col = n0 + wc * 32 + fj * 16 + (lane & 15);
      float bb3 = b3[e * DIM + col];
      int rbase = wr * 64 + fi * 16 + (lane >> 4) * 4;
#pragma unroll
      for (int r = 0; r < 4; r++) {
        int rr = rbase + r;
        if (m0 + rr < Me) {
          int pos = off + m0 + rr;
          float v = list_w[pos] * (acc[fi][fj][r] + bb3);
          atomicAdd(&y[(size_t)list_tok[pos] * DIM + col], v);
        }
      }
    }
}

extern "C" void kernel_launch(void* const* d_in, const int* in_sizes, int n_in,
                              void* d_out, int out_size, void* d_ws, size_t ws_size,
                              hipStream_t stream) {
  (void)in_sizes; (void)n_in; (void)ws_size;
  const float* x  = (const float*)d_in[0];
  const float* Wr = (const float*)d_in[1];
  const float* br = (const float*)d_in[2];
  const float* W1 = (const float*)d_in[3];
  const float* b1 = (const float*)d_in[4];
  const float* W2 = (const float*)d_in[5];
  const float* b2 = (const float*)d_in[6];
  const float* W3 = (const float*)d_in[7];
  const float* b3 = (const float*)d_in[8];
  float* y = (float*)d_out;
  char* ws = (char*)d_ws;

  const size_t matB = (size_t)NE * DFF_ * DIM * 2;     // 64 MB per transposed bf16 matrix
  size_t oW1T = 0;
  size_t oW2T = oW1T + matB;
  size_t oXbf = oW2T + matB;                           // W3T reuses oW1T after gemm1
  size_t oH   = oXbf + (size_t)T_TOK * DIM * 2;
  size_t oT2e = oH + (size_t)2 * T_TOK * DFF_ * 2;
  size_t oT2w = oT2e + (size_t)2 * T_TOK * 4;
  size_t oLtk = oT2w + (size_t)2 * T_TOK * 4;
  size_t oLw  = oLtk + (size_t)2 * T_TOK * 4;
  size_t oCtl = oLw + (size_t)2 * T_TOK * 4;

  unsigned short* W1T = (unsigned short*)(ws + oW1T);
  unsigned short* W2T = (unsigned short*)(ws + oW2T);
  unsigned short* W3T = (unsigned short*)(ws + oW1T);  // reuse
  unsigned short* Xbf = (unsigned short*)(ws + oXbf);
  unsigned short* Hb  = (unsigned short*)(ws + oH);
  int*   top2e = (int*)(ws + oT2e);
  float* top2w = (float*)(ws + oT2w);
  int*   ltok  = (int*)(ws + oLtk);
  float* lw    = (float*)(ws + oLw);
  int*   ctrl  = (int*)(ws + oCtl);

  hipMemsetAsync(y, 0, (size_t)out_size * 4, stream);
  hipMemsetAsync(ctrl, 0, (32 + 2 * MAXT) * 4, stream);

  transpose_cvt<<<dim3(DFF_ / 64, DIM / 64, NE), 256, 0, stream>>>(W1, W1T, DIM, DFF_);
  transpose_cvt<<<dim3(DFF_ / 64, DIM / 64, NE), 256, 0, stream>>>(W2, W2T, DIM, DFF_);
  router_k<<<dim3(T_TOK / 4), 256, 0, stream>>>(x, Wr, br, Xbf, top2e, top2w);
  count_k<<<dim3(T_TOK / 256), 256, 0, stream>>>(top2e, ctrl);
  scan_build<<<dim3(1), 64, 0, stream>>>(ctrl);
  scatter_k<<<dim3(T_TOK / 256), 256, 0, stream>>>(top2e, top2w, ctrl + 16, ltok, lw);
  gemm1_k<<<dim3(DFF_ / 128, MAXT - 8), 512, 0, stream>>>(Xbf, W1T, W2T, b1, b2, Hb, ltok, ctrl);
  transpose_cvt<<<dim3(DIM / 64, DFF_ / 64, NE), 256, 0, stream>>>(W3, W3T, DFF_, DIM);
  gemm2_k<<<dim3(DIM / 128, MAXT - 8), 512, 0, stream>>>(Hb, W3T, b3, ltok, lw, y, ctrl);
}

// Round 3
// 764.616 us; speedup vs baseline: 1.5050x; 1.5050x over previous
//
#include <hip/hip_runtime.h>

#define T_TOK 8192
#define DIM   1024
#define DFF_  4096
#define NE    8
#define MAXT  144

typedef float  f32x4 __attribute__((ext_vector_type(4)));
typedef __bf16 b16x8 __attribute__((ext_vector_type(8)));

__device__ __forceinline__ unsigned short f2bf(float f) {
  union { float f; unsigned int u; } v; v.f = f;
  unsigned int r = v.u + 0x7fffu + ((v.u >> 16) & 1u);
  return (unsigned short)(r >> 16);
}

__device__ __forceinline__ void gload_lds16(const void* g, void* l) {
  __builtin_amdgcn_global_load_lds((const __attribute__((address_space(1))) void*)g,
                                   (__attribute__((address_space(3))) void*)l,
                                   16, 0, 0);
}

// Explicit LDS-DMA drain: __syncthreads() alone is NOT guaranteed to wait on
// global_load_lds completion (vmcnt) before s_barrier in all compiler versions.
// Round-2 race: replay-only corruption traced to reading a freshly-DMA'd LDS
// buffer whose loads were still in flight. Always drain vmcnt before the barrier.
#define DRAIN_VMCNT() asm volatile("s_waitcnt vmcnt(0)" ::: "memory")

// ---------------- transpose + fp32->bf16 convert: src [E][R][C] -> dst [E][C][R] ----------------
__global__ __launch_bounds__(256) void transpose_cvt(const float* __restrict__ src,
                                                     unsigned short* __restrict__ dst,
                                                     int R, int C) {
  __shared__ float tile[64][65];
  size_t mat = (size_t)blockIdx.z * R * C;
  int c0 = blockIdx.x * 64, r0 = blockIdx.y * 64;
  int lc = threadIdx.x & 63, q = threadIdx.x >> 6;
  const float* s = src + mat + (size_t)r0 * C + c0;
#pragma unroll
  for (int i = 0; i < 16; i++) {
    int r = q + i * 4;
    tile[r][lc] = s[(size_t)r * C + lc];
  }
  __syncthreads();
  unsigned short* d = dst + mat + (size_t)c0 * R + r0;
#pragma unroll
  for (int i = 0; i < 16; i++) {
    int cc = q + i * 4;
    d[(size_t)cc * R + lc] = f2bf(tile[lc][cc]);
  }
}

// ---------------- router: logits (fp32 exact), top-2, softmax weights, bf16 x copy ----------------
__global__ __launch_bounds__(256) void router_k(const float* __restrict__ x,
                                                const float* __restrict__ Wr,
                                                const float* __restrict__ br,
                                                unsigned short* __restrict__ Xbf,
                                                int* __restrict__ top2e,
                                                float* __restrict__ top2w) {
  int wid = threadIdx.x >> 6, lane = threadIdx.x & 63;
  int t = blockIdx.x * 4 + wid;
  const float* xr = x + (size_t)t * DIM;
  unsigned short* xb = Xbf + (size_t)t * DIM;
  float s[NE];
#pragma unroll
  for (int e = 0; e < NE; e++) s[e] = 0.f;
  for (int i = 0; i < DIM / 64; i++) {
    int dd = i * 64 + lane;
    float xv = xr[dd];
    xb[dd] = f2bf(xv);
    const float* w = Wr + (size_t)dd * NE;
#pragma unroll
    for (int e = 0; e < NE; e++) s[e] += xv * w[e];
  }
#pragma unroll
  for (int m = 32; m >= 1; m >>= 1) {
#pragma unroll
    for (int e = 0; e < NE; e++) s[e] += __shfl_xor(s[e], m, 64);
  }
  if (lane == 0) {
#pragma unroll
    for (int e = 0; e < NE; e++) s[e] += br[e];
    int e0 = 0;
#pragma unroll
    for (int e = 1; e < NE; e++) if (s[e] > s[e0]) e0 = e;
    int e1 = (e0 == 0) ? 1 : 0;
#pragma unroll
    for (int e = 0; e < NE; e++) if (e != e0 && s[e] > s[e1]) e1 = e;
    float w0 = 1.f / (1.f + expf(s[e1] - s[e0]));  // softmax over (p0,p1), p0>=p1
    top2e[2 * t] = e0; top2e[2 * t + 1] = e1;
    top2w[2 * t] = w0; top2w[2 * t + 1] = 1.f - w0;
  }
}

// ---------------- per-block aggregated expert counting ----------------
__global__ __launch_bounds__(256) void count_k(const int* __restrict__ top2e,
                                               int* __restrict__ counts) {
  __shared__ int lcnt[NE];
  if (threadIdx.x < NE) lcnt[threadIdx.x] = 0;
  __syncthreads();
  int t = blockIdx.x * 256 + threadIdx.x;
  atomicAdd(&lcnt[top2e[2 * t]], 1);
  atomicAdd(&lcnt[top2e[2 * t + 1]], 1);
  __syncthreads();
  if (threadIdx.x < NE) atomicAdd(&counts[threadIdx.x], lcnt[threadIdx.x]);
}

// ---------------- scan + grouped-GEMM tile map (single thread; tiny) ----------------
__global__ void scan_build(int* __restrict__ ctrl) {
  if (threadIdx.x != 0 || blockIdx.x != 0) return;
  int* counts = ctrl;          // [8]
  int* offsets = ctrl + 8;     // [8]
  int* cursors = ctrl + 16;    // [8]
  int* ntile = ctrl + 24;      // [1]
  int* tileE = ctrl + 32;          // [MAXT]
  int* tileM = ctrl + 32 + MAXT;   // [MAXT]
  int o = 0;
  for (int e = 0; e < NE; e++) { offsets[e] = o; cursors[e] = o; o += counts[e]; }
  int nt = 0;
  for (int e = 0; e < NE; e++)
    for (int m0 = 0; m0 < counts[e]; m0 += 128) { tileE[nt] = e; tileM[nt] = m0; nt++; }
  ntile[0] = nt;
}

// ---------------- scatter tokens into per-expert lists (block-local ranks) ----------------
__global__ __launch_bounds__(256) void scatter_k(const int* __restrict__ top2e,
                                                 const float* __restrict__ top2w,
                                                 int* __restrict__ cursors,
                                                 int* __restrict__ list_tok,
                                                 float* __restrict__ list_w) {
  __shared__ int lcnt[NE];
  __shared__ int lbase[NE];
  int tid = threadIdx.x;
  if (tid < NE) lcnt[tid] = 0;
  __syncthreads();
  int t = blockIdx.x * 256 + tid;
  int e0 = top2e[2 * t], e1 = top2e[2 * t + 1];
  int r0 = atomicAdd(&lcnt[e0], 1);
  int r1 = atomicAdd(&lcnt[e1], 1);
  __syncthreads();
  if (tid < NE) lbase[tid] = atomicAdd(&cursors[tid], lcnt[tid]);
  __syncthreads();
  int p0 = lbase[e0] + r0, p1 = lbase[e1] + r1;
  list_tok[p0] = t; list_w[p0] = top2w[2 * t];
  list_tok[p1] = t; list_w[p1] = top2w[2 * t + 1];
}

// ---------------- grouped GEMM1 + fused SwiGLU: H = silu(X@W1+b1)*(X@W2+b2) ----------------
// 128x128 tile, BK=32, dbuf prefetch (explicit vmcnt drain + 1 barrier/K-step),
// XOR k-swizzle (2-way conflicts)
__global__ __launch_bounds__(512) void gemm1_k(const unsigned short* __restrict__ Xbf,
                                               const unsigned short* __restrict__ W1T,
                                               const unsigned short* __restrict__ W2T,
                                               const float* __restrict__ b1,
                                               const float* __restrict__ b2,
                                               unsigned short* __restrict__ H,
                                               const int* __restrict__ list_tok,
                                               const int* __restrict__ ctrl) {
  const int* counts = ctrl; const int* offsets = ctrl + 8;
  const int* ntile = ctrl + 24;
  const int* tileE = ctrl + 32; const int* tileM = ctrl + 32 + MAXT;
  int bt = blockIdx.y;
  if (bt >= ntile[0]) return;
  int e = tileE[bt], m0 = tileM[bt];
  int Me = counts[e], off = offsets[e];
  int n0 = blockIdx.x * 128;

  __shared__ unsigned short lds[2][3 * 128 * 32];  // A|B1|B2 per buf, 48 KB total

  int tid = threadIdx.x, lane = tid & 63, wid = tid >> 6;
  int wr = wid >> 2, wc = wid & 3;

  // staging: 24 chunks of 1KB per K-step (chunk = 16 rows x 32 k bf16); 3 per wave.
  // LDS written linearly (HW: chunk_base + lane*16 -> row=lane>>2, col16=lane&3);
  // global source column pre-swizzled with g(row)=(row>>1)&3 = (lane>>3)&3.
  const unsigned short* gsrc[3];
  unsigned ldsoff[3];
  {
    int lr = lane >> 2;                                // row within chunk (0..15)
    int sc = ((lane & 3) ^ ((lane >> 3) & 3)) * 8;     // swizzled k-col (elements)
#pragma unroll
    for (int j = 0; j < 3; j++) {
      int c = wid * 3 + j;
      ldsoff[j] = c * 512;
      if (c < 8) {
        int r = c * 16 + lr;
        int tok = (m0 + r < Me) ? list_tok[off + m0 + r] : list_tok[off];
        gsrc[j] = Xbf + (size_t)tok * DIM + sc;
      } else if (c < 16) {
        int n = n0 + (c - 8) * 16 + lr;
        gsrc[j] = W1T + ((size_t)e * DFF_ + n) * DIM + sc;
      } else {
        int n = n0 + (c - 16) * 16 + lr;
        gsrc[j] = W2T + ((size_t)e * DFF_ + n) * DIM + sc;
      }
    }
  }

  f32x4 acc1[4][2], acc2[4][2];
#pragma unroll
  for (int i = 0; i < 4; i++)
#pragma unroll
    for (int j = 0; j < 2; j++) {
      acc1[i][j] = f32x4{0.f, 0.f, 0.f, 0.f};
      acc2[i][j] = f32x4{0.f, 0.f, 0.f, 0.f};
    }

  // prologue: stage K-step 0 into buf 0
#pragma unroll
  for (int j = 0; j < 3; j++) gload_lds16(gsrc[j], (void*)(&lds[0][ldsoff[j]]));
  DRAIN_VMCNT();
  __syncthreads();

  int cur = 0;
  const int NK = DIM / 32;
  for (int kt = 0; kt < NK; kt++) {
    if (kt + 1 < NK) {
#pragma unroll
      for (int j = 0; j < 3; j++)
        gload_lds16(gsrc[j] + (kt + 1) * 32, (void*)(&lds[cur ^ 1][ldsoff[j]]));
    }
    const unsigned short* sA  = &lds[cur][0];
    const unsigned short* sB1 = sA + 4096;
    const unsigned short* sB2 = sA + 8192;
    int colg = lane >> 4;  // 16B k-group (0..3)
    b16x8 aF[4], bF1[2], bF2[2];
#pragma unroll
    for (int fi = 0; fi < 4; fi++) {
      int row = wr * 64 + fi * 16 + (lane & 15);
      aF[fi] = *(const b16x8*)(sA + row * 32 + ((colg ^ ((row >> 1) & 3)) * 8));
    }
#pragma unroll
    for (int fj = 0; fj < 2; fj++) {
      int row = wc * 32 + fj * 16 + (lane & 15);
      int sw = (colg ^ ((row >> 1) & 3)) * 8;
      bF1[fj] = *(const b16x8*)(sB1 + row * 32 + sw);
      bF2[fj] = *(const b16x8*)(sB2 + row * 32 + sw);
    }
#pragma unroll
    for (int fi = 0; fi < 4; fi++)
#pragma unroll
      for (int fj = 0; fj < 2; fj++) {
        acc1[fi][fj] = __builtin_amdgcn_mfma_f32_16x16x32_bf16(aF[fi], bF1[fj], acc1[fi][fj], 0, 0, 0);
        acc2[fi][fj] = __builtin_amdgcn_mfma_f32_16x16x32_bf16(aF[fi], bF2[fj], acc2[fi][fj], 0, 0, 0);
      }
    DRAIN_VMCNT();      // guarantee this iteration's prefetch DMA has landed
    __syncthreads();    // before any wave proceeds to read buf[cur^1]
    cur ^= 1;
  }

#pragma unroll
  for (int fi = 0; fi < 4; fi++)
#pragma unroll
    for (int fj = 0; fj < 2; fj++) {
      int col = n0 + wc * 32 + fj * 16 + (lane & 15);
      float bb1 = b1[e * DFF_ + col], bb2 = b2[e * DFF_ + col];
      int rbase = wr * 64 + fi * 16 + (lane >> 4) * 4;
#pragma unroll
      for (int r = 0; r < 4; r++) {
        int rr = rbase + r;
        if (m0 + rr < Me) {
          float c1 = acc1[fi][fj][r] + bb1;
          float c2 = acc2[fi][fj][r] + bb2;
          float h = c1 * c2 / (1.f + __expf(-c1));  // silu(c1)*c2
          H[(size_t)(off + m0 + rr) * DFF_ + col] = f2bf(h);
        }
      }
    }
}

// ---------------- grouped GEMM2: y[token] += w * (H @ W3^T + b3) ----------------
// 128x128 tile, BK=64, dbuf prefetch (explicit vmcnt drain), XOR k-swizzle (g(row)=row&7)
__global__ __launch_bounds__(512) void gemm2_k(const unsigned short* __restrict__ H,
                                               const unsigned short* __restrict__ W3T,
                                               const float* __restrict__ b3,
                                               const int* __restrict__ list_tok,
                                               const float* __restrict__ list_w,
                                               float* __restrict__ y,
                                               const int* __restrict__ ctrl) {
  const int* counts = ctrl; const int* offsets = ctrl + 8;
  const int* ntile = ctrl + 24;
  const int* tileE = ctrl + 32; const int* tileM = ctrl + 32 + MAXT;
  int bt = blockIdx.y;
  if (bt >= ntile[0]) return;
  int e = tileE[bt], m0 = tileM[bt];
  int Me = counts[e], off = offsets[e];
  int n0 = blockIdx.x * 128;

  __shared__ unsigned short lds[2][2 * 128 * 64];  // A|B per buf, 64 KB total

  int tid = threadIdx.x, lane = tid & 63, wid = tid >> 6;
  int wr = wid >> 2, wc = wid & 3;

  // staging: 32 chunks of 1KB per K-step (chunk = 8 rows x 64 k bf16); 4 per wave.
  const unsigned short* gsrc[4];
  unsigned ldsoff[4];
  {
    int lr = lane >> 3;                            // row within chunk (0..7)
    int sc = ((lane & 7) ^ (lane >> 3)) * 8;       // swizzled k-col, g(row)=row&7=lane>>3
#pragma unroll
    for (int j = 0; j < 4; j++) {
      int c = wid * 4 + j;
      ldsoff[j] = c * 512;
      if (c < 16) {
        int r = c * 8 + lr;
        int pos = (m0 + r < Me) ? (off + m0 + r) : off;
        gsrc[j] = H + (size_t)pos * DFF_ + sc;
      } else {
        int n = n0 + (c - 16) * 8 + lr;
        gsrc[j] = W3T + ((size_t)e * DIM + n) * DFF_ + sc;
      }
    }
  }

  f32x4 acc[4][2];
#pragma unroll
  for (int i = 0; i < 4; i++)
#pragma unroll
    for (int j = 0; j < 2; j++) acc[i][j] = f32x4{0.f, 0.f, 0.f, 0.f};

#pragma unroll
  for (int j = 0; j < 4; j++) gload_lds16(gsrc[j], (void*)(&lds[0][ldsoff[j]]));
  DRAIN_VMCNT();
  __syncthreads();

  int cur = 0;
  const int NK = DFF_ / 64;
  for (int kt = 0; kt < NK; kt++) {
    if (kt + 1 < NK) {
#pragma unroll
      for (int j = 0; j < 4; j++)
        gload_lds16(gsrc[j] + (kt + 1) * 64, (void*)(&lds[cur ^ 1][ldsoff[j]]));
    }
    const unsigned short* sA = &lds[cur][0];
    const unsigned short* sB = sA + 128 * 64;
    int colg = lane >> 4;
#pragma unroll
    for (int kk = 0; kk < 2; kk++) {
      b16x8 aF[4], bF[2];
#pragma unroll
      for (int fi = 0; fi < 4; fi++) {
        int row = wr * 64 + fi * 16 + (lane & 15);
        aF[fi] = *(const b16x8*)(sA + row * 64 + (((kk * 4 + colg) ^ (row & 7)) * 8));
      }
#pragma unroll
      for (int fj = 0; fj < 2; fj++) {
        int row = wc * 32 + fj * 16 + (lane & 15);
        bF[fj] = *(const b16x8*)(sB + row * 64 + (((kk * 4 + colg) ^ (row & 7)) * 8));
      }
#pragma unroll
      for (int fi = 0; fi < 4; fi++)
#pragma unroll
        for (int fj = 0; fj < 2; fj++)
          acc[fi][fj] = __builtin_amdgcn_mfma_f32_16x16x32_bf16(aF[fi], bF[fj], acc[fi][fj], 0, 0, 0);
    }
    DRAIN_VMCNT();      // prefetch DMA must land before next iteration's reads
    __syncthreads();
    cur ^= 1;
  }

#pragma unroll
  for (int fi = 0; fi < 4; fi++)
#pragma unroll
    for (int fj = 0; fj < 2; fj++) {
      int col = n0 + wc * 32 + fj * 16 + (lane & 15);
      float bb3 = b3[e * DIM + col];
      int rbase = wr * 64 + fi * 16 + (lane >> 4) * 4;
#pragma unroll
      for (int r = 0; r < 4; r++) {
        int rr = rbase + r;
        if (m0 + rr < Me) {
          int pos = off + m0 + rr;
          float v = list_w[pos] * (acc[fi][fj][r] + bb3);
          atomicAdd(&y[(size_t)list_tok[pos] * DIM + col], v);
        }
      }
    }
}

extern "C" void kernel_launch(void* const* d_in, const int* in_sizes, int n_in,
                              void* d_out, int out_size, void* d_ws, size_t ws_size,
                              hipStream_t stream) {
  (void)in_sizes; (void)n_in; (void)ws_size;
  const float* x  = (const float*)d_in[0];
  const float* Wr = (const float*)d_in[1];
  const float* br = (const float*)d_in[2];
  const float* W1 = (const float*)d_in[3];
  const float* b1 = (const float*)d_in[4];
  const float* W2 = (const float*)d_in[5];
  const float* b2 = (const float*)d_in[6];
  const float* W3 = (const float*)d_in[7];
  const float* b3 = (const float*)d_in[8];
  float* y = (float*)d_out;
  char* ws = (char*)d_ws;

  const size_t matB = (size_t)NE * DFF_ * DIM * 2;     // 64 MB per transposed bf16 matrix
  size_t oW1T = 0;
  size_t oW2T = oW1T + matB;
  size_t oXbf = oW2T + matB;                           // W3T reuses oW1T after gemm1
  size_t oH   = oXbf + (size_t)T_TOK * DIM * 2;
  size_t oT2e = oH + (size_t)2 * T_TOK * DFF_ * 2;
  size_t oT2w = oT2e + (size_t)2 * T_TOK * 4;
  size_t oLtk = oT2w + (size_t)2 * T_TOK * 4;
  size_t oLw  = oLtk + (size_t)2 * T_TOK * 4;
  size_t oCtl = oLw + (size_t)2 * T_TOK * 4;

  unsigned short* W1T = (unsigned short*)(ws + oW1T);
  unsigned short* W2T = (unsigned short*)(ws + oW2T);
  unsigned short* W3T = (unsigned short*)(ws + oW1T);  // reuse
  unsigned short* Xbf = (unsigned short*)(ws + oXbf);
  unsigned short* Hb  = (unsigned short*)(ws + oH);
  int*   top2e = (int*)(ws + oT2e);
  float* top2w = (float*)(ws + oT2w);
  int*   ltok  = (int*)(ws + oLtk);
  float* lw    = (float*)(ws + oLw);
  int*   ctrl  = (int*)(ws + oCtl);

  hipMemsetAsync(y, 0, (size_t)out_size * 4, stream);
  hipMemsetAsync(ctrl, 0, (32 + 2 * MAXT) * 4, stream);

  transpose_cvt<<<dim3(DFF_ / 64, DIM / 64, NE), 256, 0, stream>>>(W1, W1T, DIM, DFF_);
  transpose_cvt<<<dim3(DFF_ / 64, DIM / 64, NE), 256, 0, stream>>>(W2, W2T, DIM, DFF_);
  router_k<<<dim3(T_TOK / 4), 256, 0, stream>>>(x, Wr, br, Xbf, top2e, top2w);
  count_k<<<dim3(T_TOK / 256), 256, 0, stream>>>(top2e, ctrl);
  scan_build<<<dim3(1), 64, 0, stream>>>(ctrl);
  scatter_k<<<dim3(T_TOK / 256), 256, 0, stream>>>(top2e, top2w, ctrl + 16, ltok, lw);
  gemm1_k<<<dim3(DFF_ / 128, MAXT - 8), 512, 0, stream>>>(Xbf, W1T, W2T, b1, b2, Hb, ltok, ctrl);
  transpose_cvt<<<dim3(DIM / 64, DFF_ / 64, NE), 256, 0, stream>>>(W3, W3T, DFF_, DIM);
  gemm2_k<<<dim3(DIM / 128, MAXT - 8), 512, 0, stream>>>(Hb, W3T, b3, ltok, lw, y, ctrl);
}